// Round 11
// baseline (5257.190 us; speedup 1.0000x reference)
//
#include <hip/hip_runtime.h>

// Problem constants
#define NXd 512
#define NUd 64
#define NBd 64
#define NYd 32
#define TTd 1024
#define LSZ (NXd * NXd)   // 262144, one layer's square matrix
#define KWL (NXd * NUd)   // 32768, one layer's Kw

// Persistent-kernel decomposition
#define CHAINS 16   // independent batch groups (4 b-rows each)
#define GWG 16      // workgroups per chain (32 cols each)
#define BPC 4       // batch rows per chain
#define CPW 32      // output columns per workgroup

typedef float f32x4 __attribute__((ext_vector_type(4)));
typedef unsigned u32x4 __attribute__((ext_vector_type(4)));

// Device-scope (LLC coherence point) store — the proven-correct exchange path.
#define AT_STORE(p, v) __hip_atomic_store((p), (v), __ATOMIC_RELAXED, __HIP_MEMORY_SCOPE_AGENT)

// ---------------- precompute kernels ----------------

// X0 = 2I - E   (first Newton-Schulz iterate for E^{-1})
__global__ void k_x0(const float* __restrict__ E, float* __restrict__ X0) {
  int idx = blockIdx.x * 256 + threadIdx.x;
  if (idx >= 2 * LSZ) return;
  int m = idx & (LSZ - 1);
  int i = m >> 9, j = m & (NXd - 1);
  X0[idx] = (i == j ? 2.0f : 0.0f) - E[idx];
}

// C = A@B  (NEWTON=0)  or  C = 2A - A@B  (NEWTON=1); batched over z (stride LSZ)
template <int NEWTON>
__global__ __launch_bounds__(256) void k_mm(const float* __restrict__ A,
                                            const float* __restrict__ B,
                                            float* __restrict__ C) {
  __shared__ __align__(16) float As[16][68];
  __shared__ __align__(16) float Bs[16][68];
  const int z = blockIdx.z;
  A += (size_t)z * LSZ; B += (size_t)z * LSZ; C += (size_t)z * LSZ;
  const int i0 = blockIdx.y * 64, j0 = blockIdx.x * 64;
  const int tid = threadIdx.x;
  const int ty = tid >> 4, tx = tid & 15;
  const int aII = tid >> 2, aKQ = (tid & 3) * 4;
  const int bKK = tid >> 4, bJQ = (tid & 15) * 4;
  float acc[4][4] = {};
  for (int k0 = 0; k0 < NXd; k0 += 16) {
    float4 av = *(const float4*)&A[(size_t)(i0 + aII) * NXd + k0 + aKQ];
    float4 bv = *(const float4*)&B[(size_t)(k0 + bKK) * NXd + j0 + bJQ];
    As[aKQ + 0][aII] = av.x; As[aKQ + 1][aII] = av.y;
    As[aKQ + 2][aII] = av.z; As[aKQ + 3][aII] = av.w;
    *(float4*)&Bs[bKK][bJQ] = bv;
    __syncthreads();
#pragma unroll
    for (int kk = 0; kk < 16; ++kk) {
      float4 a4 = *(const float4*)&As[kk][ty * 4];
      float4 b4 = *(const float4*)&Bs[kk][tx * 4];
      float av4[4] = {a4.x, a4.y, a4.z, a4.w};
      float bv4[4] = {b4.x, b4.y, b4.z, b4.w};
#pragma unroll
      for (int i = 0; i < 4; ++i)
#pragma unroll
        for (int j = 0; j < 4; ++j) acc[i][j] = fmaf(av4[i], bv4[j], acc[i][j]);
    }
    __syncthreads();
  }
#pragma unroll
  for (int i = 0; i < 4; ++i)
#pragma unroll
    for (int j = 0; j < 4; ++j) {
      int r = i0 + ty * 4 + i, cc = j0 + tx * 4 + j;
      float v = acc[i][j];
      if (NEWTON) v = 2.0f * A[(size_t)r * NXd + cc] - v;
      C[(size_t)r * NXd + cc] = v;
    }
}

// C[r][c] = sum_k A[r][k] * B[c][k]   (A@B^T), ragged N, batched via explicit strides
__global__ __launch_bounds__(256) void k_mm_abt(const float* __restrict__ A,
                                                const float* __restrict__ B,
                                                float* __restrict__ C,
                                                int ncols, int ldC,
                                                int aStride, int bStride, int cStride) {
  __shared__ __align__(16) float As[16][68];
  __shared__ __align__(16) float Bs[16][68];
  const int z = blockIdx.z;
  A += (ptrdiff_t)z * aStride; B += (ptrdiff_t)z * bStride; C += (ptrdiff_t)z * cStride;
  const int i0 = blockIdx.y * 64, j0 = blockIdx.x * 64;
  const int tid = threadIdx.x;
  const int ty = tid >> 4, tx = tid & 15;
  const int aII = tid >> 2, aKQ = (tid & 3) * 4;
  float acc[4][4] = {};
  for (int k0 = 0; k0 < NXd; k0 += 16) {
    float4 av = *(const float4*)&A[(size_t)(i0 + aII) * NXd + k0 + aKQ];
    float4 bv = make_float4(0.f, 0.f, 0.f, 0.f);
    if (j0 + aII < ncols) bv = *(const float4*)&B[(size_t)(j0 + aII) * NXd + k0 + aKQ];
    As[aKQ + 0][aII] = av.x; As[aKQ + 1][aII] = av.y;
    As[aKQ + 2][aII] = av.z; As[aKQ + 3][aII] = av.w;
    Bs[aKQ + 0][aII] = bv.x; Bs[aKQ + 1][aII] = bv.y;
    Bs[aKQ + 2][aII] = bv.z; Bs[aKQ + 3][aII] = bv.w;
    __syncthreads();
#pragma unroll
    for (int kk = 0; kk < 16; ++kk) {
      float4 a4 = *(const float4*)&As[kk][ty * 4];
      float4 b4 = *(const float4*)&Bs[kk][tx * 4];
      float av4[4] = {a4.x, a4.y, a4.z, a4.w};
      float bv4[4] = {b4.x, b4.y, b4.z, b4.w};
#pragma unroll
      for (int i = 0; i < 4; ++i)
#pragma unroll
        for (int j = 0; j < 4; ++j) acc[i][j] = fmaf(av4[i], bv4[j], acc[i][j]);
    }
    __syncthreads();
  }
#pragma unroll
  for (int i = 0; i < 4; ++i)
#pragma unroll
    for (int j = 0; j < 4; ++j) {
      int r = i0 + ty * 4 + i, cc = j0 + tx * 4 + j;
      if (cc < ncols) C[(size_t)r * ldC + cc] = acc[i][j];
    }
}

// G1 = relu(Hb0 + u_0 @ Kw0^T) [parity 0]; G2 reset to parity-1 pattern
// (replay determinism!); y[:, :, 0] = Cb.
__global__ void k_init(const float* __restrict__ ug, const float* __restrict__ Kwg,
                       const float* __restrict__ Hbg, const float* __restrict__ Cbg,
                       float* __restrict__ G1g, unsigned* __restrict__ G2u,
                       float* __restrict__ yg) {
  __shared__ float su[NUd];
  const int b = blockIdx.x, tid = threadIdx.x;
  if (tid < NUd) su[tid] = ug[(size_t)b * NUd * TTd + (size_t)tid * TTd];
  __syncthreads();
  for (int i = tid; i < NXd; i += 256) {
    float acc = Hbg[i];  // layer 0 bias
#pragma unroll 8
    for (int k = 0; k < NUd; ++k) acc = fmaf(su[k], Kwg[i * NUd + k], acc);
    AT_STORE(&G1g[b * NXd + i], fmaxf(acc, 0.f));
    AT_STORE(&G2u[b * NXd + i], 0x80000000u);
  }
  if (tid < NYd) yg[(size_t)b * NYd * TTd + (size_t)tid * TTd] = Cbg[tid];
}

// ---------------- persistent recurrence kernel ----------------
// grid = 256 WGs x 256 threads; chain = blockIdx&15, g = blockIdx>>4 owns
// cols [g*32, g*32+32). Parity-tagged zero-barrier exchange via LLC (sc0 sc1)
// with the MONOLITHIC load+waitcnt poll asm (rounds 3/5/6 — in-flight load
// destinations never cross an asm-block boundary). This round's safe deltas:
// double-buffered sG, wave0-only shuffle-reduced y (barrier-free, overlapped
// with partner commit+detect), pure hot-spin polling.
__global__ __launch_bounds__(256, 1) void k_rnn(
    const float* __restrict__ M0g, const float* __restrict__ M1g,
    const float* __restrict__ PPg, const float* __restrict__ ug,
    const float* __restrict__ Kwg, const float* __restrict__ Hbg,
    const float* __restrict__ Cbg,
    float* __restrict__ G1g, float* __restrict__ G2g,
    float* __restrict__ yg) {
  __shared__ __align__(16) float sGA[BPC][640];    // skewed: idx = k + (k>>4)*4
  __shared__ __align__(16) float sGB[BPC][640];
  __shared__ __align__(16) float sPP[2][516];
  __shared__ __align__(16) float sU[BPC][NUd];
  __shared__ __align__(16) float sR1[32][4][36];   // [kg][row][col(+pad)]
  __shared__ __align__(16) float sR2[8][4][36];    // [kg4][row][col(+pad)]

  const int tid = (int)threadIdx.x;
  const int chain = (int)blockIdx.x & 15;
  const int g = (int)blockIdx.x >> 4;
  const int i0 = g * CPW;
  const int b0 = chain * BPC;

  // FMA thread map
  const int kg = tid >> 3;          // 32 K-groups of 16
  const int c4 = (tid & 7) * 4;     // 4 owned output cols

  // ---- weights into registers (round-6 form, proven resident) ----
  f32x4 w1[16], w0[16];
#pragma unroll
  for (int kk = 0; kk < 16; ++kk) {
    w1[kk] = *(const f32x4*)&M1g[(size_t)(kg * 16 + kk) * NXd + i0 + c4];
    w0[kk] = *(const f32x4*)&M0g[(size_t)(kg * 16 + kk) * NXd + i0 + c4];
  }
  f32x4 kw1[2], kw0[2];
#pragma unroll
  for (int j = 0; j < 2; ++j) {
    const int uk = kg * 2 + j;
#pragma unroll
    for (int cc = 0; cc < 4; ++cc) {
      kw1[j][cc] = Kwg[KWL + (i0 + c4 + cc) * NUd + uk];
      kw0[j][cc] = Kwg[(i0 + c4 + cc) * NUd + uk];
    }
  }

  // y-projection weights (2 cols per WG) into LDS
  for (int n = tid; n < NXd * 2; n += 256) {
    int k = n >> 1, q = n & 1;
    sPP[q][k] = PPg[k * NYd + g * 2 + q];
  }

  const float cbr = Cbg[g * 2 + (tid & 1)];
  f32x4 hb0_4 = {0.f, 0.f, 0.f, 0.f}, hb1_4 = {0.f, 0.f, 0.f, 0.f};
  if (tid < 32) {
    hb0_4 = *(const f32x4*)&Hbg[i0 + c4];
    hb1_4 = *(const f32x4*)&Hbg[NXd + i0 + c4];
  }

  // per-thread u element stream: (b0+ub, uk, t), float4-cached over t
  const int ub = tid >> 6, uk = tid & 63;
  const float* Ub = ug + (size_t)(b0 + ub) * (NUd * TTd) + (size_t)uk * TTd;
  float4 ucv = *(const float4*)Ub;
  sU[ub][uk] = ucv.x;  // u_0

  bool gaveup = false;  // sticky: a stuck poll degrades to wrong answer, not a hang

  // Poll-stage this chain's 4x512 G tile (8KB) from LLC into skewed LDS.
  // Loads + vmcnt(0) live in ONE asm block — in-flight destinations never
  // visible to the compiler's register allocator. Pure hot spin (1 WG/CU).
  auto stage_g = [&](const float* __restrict__ src, unsigned pbit,
                     float (*dst)[640]) {
    const unsigned* p0 = (const unsigned*)(src + tid * 8);
    u32x4 a, b;
    if (!gaveup) {
      int spins = 0;
      for (;;) {
        asm volatile(
            "global_load_dwordx4 %0, %2, off sc0 sc1\n\t"
            "global_load_dwordx4 %1, %2, off offset:16 sc0 sc1\n\t"
            "s_waitcnt vmcnt(0)"
            : "=&v"(a), "=&v"(b)
            : "v"(p0)
            : "memory");
        unsigned m = (a.x ^ pbit) | (a.y ^ pbit) | (a.z ^ pbit) | (a.w ^ pbit) |
                     (b.x ^ pbit) | (b.y ^ pbit) | (b.z ^ pbit) | (b.w ^ pbit);
        if (!(m & 0x80000000u)) break;
        if (++spins > 2000000) { gaveup = true; break; }
      }
    } else {
      asm volatile(
          "global_load_dwordx4 %0, %2, off sc0 sc1\n\t"
          "global_load_dwordx4 %1, %2, off offset:16 sc0 sc1\n\t"
          "s_waitcnt vmcnt(0)"
          : "=&v"(a), "=&v"(b)
          : "v"(p0)
          : "memory");
    }
    const int bb = tid >> 6;
    const int kk = (tid * 8) & 511;
    const int li = kk + ((kk >> 4) << 2);  // skewed index (kk%16 in {0,8})
    u32x4 am = {a.x & 0x7fffffffu, a.y & 0x7fffffffu,
                a.z & 0x7fffffffu, a.w & 0x7fffffffu};
    u32x4 bm = {b.x & 0x7fffffffu, b.y & 0x7fffffffu,
                b.z & 0x7fffffffu, b.w & 0x7fffffffu};
    *(u32x4*)&dst[bb][li] = am;
    *(u32x4*)&dst[bb][li + 4] = bm;
  };

  // Main phase: reg-weight FMAs -> 2-stage LDS reduce -> parity-tagged store.
  auto phase_main = [&](const f32x4* w, const f32x4* kw, const f32x4& hb4,
                        const float (*sGb)[640], float* __restrict__ Gdst,
                        unsigned pbit) {
    f32x4 acc0 = {0.f, 0.f, 0.f, 0.f}, acc1 = acc0, acc2 = acc0, acc3 = acc0;
    const int gb = kg * 20;  // skewed base of this thread's 16-K slice
#pragma unroll
    for (int blk = 0; blk < 4; ++blk) {
      f32x4 g0 = *(const f32x4*)&sGb[0][gb + blk * 4];
      f32x4 g1 = *(const f32x4*)&sGb[1][gb + blk * 4];
      f32x4 g2 = *(const f32x4*)&sGb[2][gb + blk * 4];
      f32x4 g3 = *(const f32x4*)&sGb[3][gb + blk * 4];
#pragma unroll
      for (int q = 0; q < 4; ++q) {
        f32x4 wv = w[blk * 4 + q];
        acc0 += wv * g0[q];
        acc1 += wv * g1[q];
        acc2 += wv * g2[q];
        acc3 += wv * g3[q];
      }
    }
#pragma unroll
    for (int j = 0; j < 2; ++j) {
      f32x4 wv = kw[j];
      const int us = kg * 2 + j;
      acc0 += wv * sU[0][us];
      acc1 += wv * sU[1][us];
      acc2 += wv * sU[2][us];
      acc3 += wv * sU[3][us];
    }
    // stage 1: per-kg partials
    *(f32x4*)&sR1[kg][0][c4] = acc0;
    *(f32x4*)&sR1[kg][1][c4] = acc1;
    *(f32x4*)&sR1[kg][2][c4] = acc2;
    *(f32x4*)&sR1[kg][3][c4] = acc3;
    __syncthreads();
    // stage 2: 32 -> 8 partials (all 256 threads)
    {
      const int kg4 = tid >> 5, r2 = (tid >> 3) & 3, cc = (tid & 7) * 4;
      f32x4 s = *(const f32x4*)&sR1[kg4 * 4 + 0][r2][cc];
      s += *(const f32x4*)&sR1[kg4 * 4 + 1][r2][cc];
      s += *(const f32x4*)&sR1[kg4 * 4 + 2][r2][cc];
      s += *(const f32x4*)&sR1[kg4 * 4 + 3][r2][cc];
      *(f32x4*)&sR2[kg4][r2][cc] = s;
    }
    __syncthreads();
    // stage 3: 8 -> 1, bias, relu, tag, store (32 threads)
    if (tid < 32) {
      const int bb = tid >> 3;  // c4 == (tid&7)*4 already
      f32x4 s = *(const f32x4*)&sR2[0][bb][c4];
#pragma unroll
      for (int k4 = 1; k4 < 8; ++k4) s += *(const f32x4*)&sR2[k4][bb][c4];
      s += hb4;
      u32x4 uv;
      uv.x = __float_as_uint(fmaxf(s.x, 0.f)) | pbit;
      uv.y = __float_as_uint(fmaxf(s.y, 0.f)) | pbit;
      uv.z = __float_as_uint(fmaxf(s.z, 0.f)) | pbit;
      uv.w = __float_as_uint(fmaxf(s.w, 0.f)) | pbit;
      float* gp = Gdst + (size_t)(b0 + bb) * NXd + i0 + c4;
      asm volatile("global_store_dwordx4 %0, %1, off sc0 sc1"
                   :: "v"(gp), "v"(uv) : "memory");
    }
  };

  // y projection: wave-0-only, barrier-free. 64 lanes compute partials over
  // sGB (all writes made visible by the __syncthreads BEFORE phase_main B),
  // then an in-wave __shfl_xor butterfly (strides 8/16/32) reduces the 8
  // K-segments; lanes 0..7 hold totals. No LDS, no waitcnt hazards. Runs
  // after the G-store issues -> overlapped with partner commit+detect.
  // sGB is not rewritten until next iteration's phase-B stage_g, which all
  // waves reach only after passing phase_main A's barriers (wave 0 included).
  auto y_wave0 = [&](const float (*sGb)[640], int tOut) {
    if (tid < 64) {
      int ks = tid >> 3, bb = (tid >> 1) & 3, q = tid & 1;
      const int base = ks * 80;  // skewed base of ks*64
      float p = 0.f;
#pragma unroll
      for (int kk = 0; kk < 64; kk += 4) {
        const int li = base + kk + ((kk >> 4) << 2);
        f32x4 gv = *(const f32x4*)&sGb[bb][li];
        f32x4 pv = *(const f32x4*)&sPP[q][ks * 64 + kk];
        p = fmaf(gv.x, pv.x, p); p = fmaf(gv.y, pv.y, p);
        p = fmaf(gv.z, pv.z, p); p = fmaf(gv.w, pv.w, p);
      }
      p += __shfl_xor(p, 8, 64);
      p += __shfl_xor(p, 16, 64);
      p += __shfl_xor(p, 32, 64);
      if (tid < 8) {
        int bb3 = tid >> 1, q3 = tid & 1;  // matches bb,q for lanes 0..7
        yg[(size_t)(b0 + bb3) * (NYd * TTd) + (size_t)(g * 2 + q3) * TTd + tOut] =
            p + cbr;
      }
    }
  };

  // Parity schedule: G2 written at A(t) with parity t&1, read at B(t) with
  // t&1. G1 written at B(t) with parity (t+1)&1, read at A(t+1); k_init is
  // "B(-1)" writing parity 0, matching A(0).
  const float* G1c = G1g + (size_t)b0 * NXd;  // chain-local row base
  const float* G2c = G2g + (size_t)b0 * NXd;
  for (int t = 0; t < TTd - 1; ++t) {
    const unsigned pb = (unsigned)(t & 1) << 31;
    // phase A: G2 = relu(G1@M1 + Hb1 + u_t@Kw1^T)
    stage_g(G1c, pb, sGA);
    __syncthreads();
    phase_main(w1, kw1, hb1_4, sGA, G2g, pb);

    // phase B: G1 = relu(G2@M0 + Hb0 + u_{t+1}@Kw0^T); y_{t+1} = G2@PP + Cb
    stage_g(G2c, pb, sGB);
    {
      int tt = t + 1;
      if ((tt & 3) == 0) ucv = *(const float4*)(Ub + tt);
      int comp = tt & 3;
      float uv = (comp & 2) ? ((comp & 1) ? ucv.w : ucv.z)
                            : ((comp & 1) ? ucv.y : ucv.x);
      sU[ub][uk] = uv;
    }
    __syncthreads();
    phase_main(w0, kw0, hb0_4, sGB, G1g, pb ^ 0x80000000u);
    y_wave0(sGB, t + 1);  // wave 0 only; waves 1-3 already poll next tile
  }
}

// ---------------- launch ----------------
extern "C" void kernel_launch(void* const* d_in, const int* in_sizes, int n_in,
                              void* d_out, int out_size, void* d_ws, size_t ws_size,
                              hipStream_t stream) {
  (void)in_sizes; (void)n_in; (void)out_size; (void)ws_size;
  const float* u  = (const float*)d_in[0];
  const float* E  = (const float*)d_in[1];
  const float* Kw = (const float*)d_in[2];
  const float* Hw = (const float*)d_in[3];
  const float* Hb = (const float*)d_in[4];
  const float* Cw = (const float*)d_in[5];
  const float* Cb = (const float*)d_in[6];
  float* y = (float*)d_out;
  float* ws = (float*)d_ws;

  float* R0 = ws;                 // 2*LSZ
  float* R1 = ws + 2 * LSZ;       // 2*LSZ
  float* R2 = ws + 4 * LSZ;       // 2*LSZ
  float* M0 = ws + 6 * LSZ;       // LSZ
  float* M1 = M0 + LSZ;           // LSZ
  float* PPb = ws + 8 * LSZ;      // NX*NY
  float* G1 = PPb + NXd * NYd;    // NB*NX
  float* G2 = G1 + NBd * NXd;     // NB*NX

  // Einv via Newton-Schulz: X0 = 2I - E; X_{n+1} = 2X_n - X_n(E X_n), 2 iters
  k_x0<<<dim3((2 * LSZ + 255) / 256), dim3(256), 0, stream>>>(E, R0);
  k_mm<0><<<dim3(8, 8, 2), dim3(256), 0, stream>>>(E, R0, R1);   // T1 = E@X0
  k_mm<1><<<dim3(8, 8, 2), dim3(256), 0, stream>>>(R0, R1, R2);  // X1 = 2X0 - X0@T1
  k_mm<0><<<dim3(8, 8, 2), dim3(256), 0, stream>>>(E, R2, R0);   // T2 = E@X1
  k_mm<1><<<dim3(8, 8, 2), dim3(256), 0, stream>>>(R2, R0, R1);  // X2 = Einv (in R1)

  // M0 = Einv1@Hw0^T, M1 = Einv0@Hw1^T  (z flips the Einv layer)
  k_mm_abt<<<dim3(8, 8, 2), dim3(256), 0, stream>>>(R1 + LSZ, Hw, M0,
                                                    512, 512, -LSZ, LSZ, LSZ);
  // PP = Einv1@Cw^T
  k_mm_abt<<<dim3(1, 8, 1), dim3(256), 0, stream>>>(R1 + LSZ, Cw, PPb,
                                                    32, 32, 0, 0, 0);
  // G1 = relu(Hb0 + u_0@Kw0^T) [parity 0], G2 := parity-1 reset, y[:,:,0] = Cb
  k_init<<<dim3(64), dim3(256), 0, stream>>>(u, Kw, Hb, Cb, G1, (unsigned*)G2, y);
  // serial recurrence, 16 chains x 16 WGs, zero-barrier parity exchange (LLC)
  k_rnn<<<dim3(256), dim3(256), 0, stream>>>(M0, M1, PPb, u, Kw, Hb, Cb,
                                             G1, G2, y);
}

// Round 12
// 4146.368 us; speedup vs baseline: 1.2679x; 1.2679x over previous
//
#include <hip/hip_runtime.h>

// Problem constants
#define NXd 512
#define NUd 64
#define NBd 64
#define NYd 32
#define TTd 1024
#define LSZ (NXd * NXd)   // 262144, one layer's square matrix
#define KWL (NXd * NUd)   // 32768, one layer's Kw

// Persistent-kernel decomposition
#define CHAINS 16   // independent batch groups (4 b-rows each)
#define GWG 16      // workgroups per chain (32 cols each)
#define BPC 4       // batch rows per chain
#define CPW 32      // output columns per workgroup

typedef float f32x4 __attribute__((ext_vector_type(4)));
typedef unsigned u32x4 __attribute__((ext_vector_type(4)));

// LLC-coherent (cache-bypassing) accesses
#define AT_STORE(p, v) __hip_atomic_store((p), (v), __ATOMIC_RELAXED, __HIP_MEMORY_SCOPE_AGENT)

// ---------------- precompute kernels ----------------

// X0 = 2I - E   (first Newton-Schulz iterate for E^{-1})
__global__ void k_x0(const float* __restrict__ E, float* __restrict__ X0) {
  int idx = blockIdx.x * 256 + threadIdx.x;
  if (idx >= 2 * LSZ) return;
  int m = idx & (LSZ - 1);
  int i = m >> 9, j = m & (NXd - 1);
  X0[idx] = (i == j ? 2.0f : 0.0f) - E[idx];
}

// C = A@B  (NEWTON=0)  or  C = 2A - A@B  (NEWTON=1); batched over z (stride LSZ)
template <int NEWTON>
__global__ __launch_bounds__(256) void k_mm(const float* __restrict__ A,
                                            const float* __restrict__ B,
                                            float* __restrict__ C) {
  __shared__ __align__(16) float As[16][68];
  __shared__ __align__(16) float Bs[16][68];
  const int z = blockIdx.z;
  A += (size_t)z * LSZ; B += (size_t)z * LSZ; C += (size_t)z * LSZ;
  const int i0 = blockIdx.y * 64, j0 = blockIdx.x * 64;
  const int tid = threadIdx.x;
  const int ty = tid >> 4, tx = tid & 15;
  const int aII = tid >> 2, aKQ = (tid & 3) * 4;
  const int bKK = tid >> 4, bJQ = (tid & 15) * 4;
  float acc[4][4] = {};
  for (int k0 = 0; k0 < NXd; k0 += 16) {
    float4 av = *(const float4*)&A[(size_t)(i0 + aII) * NXd + k0 + aKQ];
    float4 bv = *(const float4*)&B[(size_t)(k0 + bKK) * NXd + j0 + bJQ];
    As[aKQ + 0][aII] = av.x; As[aKQ + 1][aII] = av.y;
    As[aKQ + 2][aII] = av.z; As[aKQ + 3][aII] = av.w;
    *(float4*)&Bs[bKK][bJQ] = bv;
    __syncthreads();
#pragma unroll
    for (int kk = 0; kk < 16; ++kk) {
      float4 a4 = *(const float4*)&As[kk][ty * 4];
      float4 b4 = *(const float4*)&Bs[kk][tx * 4];
      float av4[4] = {a4.x, a4.y, a4.z, a4.w};
      float bv4[4] = {b4.x, b4.y, b4.z, b4.w};
#pragma unroll
      for (int i = 0; i < 4; ++i)
#pragma unroll
        for (int j = 0; j < 4; ++j) acc[i][j] = fmaf(av4[i], bv4[j], acc[i][j]);
    }
    __syncthreads();
  }
#pragma unroll
  for (int i = 0; i < 4; ++i)
#pragma unroll
    for (int j = 0; j < 4; ++j) {
      int r = i0 + ty * 4 + i, cc = j0 + tx * 4 + j;
      float v = acc[i][j];
      if (NEWTON) v = 2.0f * A[(size_t)r * NXd + cc] - v;
      C[(size_t)r * NXd + cc] = v;
    }
}

// C[r][c] = sum_k A[r][k] * B[c][k]   (A@B^T), ragged N, batched via explicit strides
__global__ __launch_bounds__(256) void k_mm_abt(const float* __restrict__ A,
                                                const float* __restrict__ B,
                                                float* __restrict__ C,
                                                int ncols, int ldC,
                                                int aStride, int bStride, int cStride) {
  __shared__ __align__(16) float As[16][68];
  __shared__ __align__(16) float Bs[16][68];
  const int z = blockIdx.z;
  A += (ptrdiff_t)z * aStride; B += (ptrdiff_t)z * bStride; C += (ptrdiff_t)z * cStride;
  const int i0 = blockIdx.y * 64, j0 = blockIdx.x * 64;
  const int tid = threadIdx.x;
  const int ty = tid >> 4, tx = tid & 15;
  const int aII = tid >> 2, aKQ = (tid & 3) * 4;
  float acc[4][4] = {};
  for (int k0 = 0; k0 < NXd; k0 += 16) {
    float4 av = *(const float4*)&A[(size_t)(i0 + aII) * NXd + k0 + aKQ];
    float4 bv = make_float4(0.f, 0.f, 0.f, 0.f);
    if (j0 + aII < ncols) bv = *(const float4*)&B[(size_t)(j0 + aII) * NXd + k0 + aKQ];
    As[aKQ + 0][aII] = av.x; As[aKQ + 1][aII] = av.y;
    As[aKQ + 2][aII] = av.z; As[aKQ + 3][aII] = av.w;
    Bs[aKQ + 0][aII] = bv.x; Bs[aKQ + 1][aII] = bv.y;
    Bs[aKQ + 2][aII] = bv.z; Bs[aKQ + 3][aII] = bv.w;
    __syncthreads();
#pragma unroll
    for (int kk = 0; kk < 16; ++kk) {
      float4 a4 = *(const float4*)&As[kk][ty * 4];
      float4 b4 = *(const float4*)&Bs[kk][tx * 4];
      float av4[4] = {a4.x, a4.y, a4.z, a4.w};
      float bv4[4] = {b4.x, b4.y, b4.z, b4.w};
#pragma unroll
      for (int i = 0; i < 4; ++i)
#pragma unroll
        for (int j = 0; j < 4; ++j) acc[i][j] = fmaf(av4[i], bv4[j], acc[i][j]);
    }
    __syncthreads();
  }
#pragma unroll
  for (int i = 0; i < 4; ++i)
#pragma unroll
    for (int j = 0; j < 4; ++j) {
      int r = i0 + ty * 4 + i, cc = j0 + tx * 4 + j;
      if (cc < ncols) C[(size_t)r * ldC + cc] = acc[i][j];
    }
}

// G1 = relu(Hb0 + u_0 @ Kw0^T) [parity 0]; G2 reset to parity-1 pattern
// (replay determinism!); y[:, :, 0] = Cb.
__global__ void k_init(const float* __restrict__ ug, const float* __restrict__ Kwg,
                       const float* __restrict__ Hbg, const float* __restrict__ Cbg,
                       float* __restrict__ G1g, unsigned* __restrict__ G2u,
                       float* __restrict__ yg) {
  __shared__ float su[NUd];
  const int b = blockIdx.x, tid = threadIdx.x;
  if (tid < NUd) su[tid] = ug[(size_t)b * NUd * TTd + (size_t)tid * TTd];
  __syncthreads();
  for (int i = tid; i < NXd; i += 256) {
    float acc = Hbg[i];  // layer 0 bias
#pragma unroll 8
    for (int k = 0; k < NUd; ++k) acc = fmaf(su[k], Kwg[i * NUd + k], acc);
    AT_STORE(&G1g[b * NXd + i], fmaxf(acc, 0.f));
    AT_STORE(&G2u[b * NXd + i], 0x80000000u);
  }
  if (tid < NYd) yg[(size_t)b * NYd * TTd + (size_t)tid * TTd] = Cbg[tid];
}

// ---------------- persistent recurrence kernel ----------------
// grid = 256 WGs x 256 threads; chain = blockIdx&15, g = blockIdx>>4 owns
// cols [g*32, g*32+32). Parity-tagged zero-barrier exchange (see round 3/5).
// Weights live in REGISTERS (phase-invariant; 1 wave/SIMD so VGPRs are
// free); thread map (kg=tid>>3 K-groups of 16, c4=(tid&7)*4 cols) cuts
// per-thread LDS G reads 80->16 b128. Skewed sG (+4 floats per 16) makes the
// kg-strided reads bank-conflict-free.
__global__ __launch_bounds__(256, 1) void k_rnn(
    const float* __restrict__ M0g, const float* __restrict__ M1g,
    const float* __restrict__ PPg, const float* __restrict__ ug,
    const float* __restrict__ Kwg, const float* __restrict__ Hbg,
    const float* __restrict__ Cbg,
    float* __restrict__ G1g, float* __restrict__ G2g,
    float* __restrict__ yg) {
  __shared__ __align__(16) float sG[BPC][640];     // skewed: idx = k + (k>>4)*4
  __shared__ __align__(16) float sPP[2][516];
  __shared__ __align__(16) float sU[BPC][NUd];
  __shared__ __align__(16) float sR1[32][4][36];   // [kg][row][col(+pad)]
  __shared__ __align__(16) float sR2[8][4][36];    // [kg4][row][col(+pad)]
  __shared__ __align__(16) float sRedY[8][BPC][2];

  const int tid = (int)threadIdx.x;
  const int chain = (int)blockIdx.x & 15;
  const int g = (int)blockIdx.x >> 4;
  const int i0 = g * CPW;
  const int b0 = chain * BPC;

  // FMA thread map
  const int kg = tid >> 3;          // 32 K-groups of 16
  const int c4 = (tid & 7) * 4;     // 4 owned output cols

  // ---- weights into registers (static indexing only -> no scratch) ----
  f32x4 w1[16], w0[16];
#pragma unroll
  for (int kk = 0; kk < 16; ++kk) {
    w1[kk] = *(const f32x4*)&M1g[(size_t)(kg * 16 + kk) * NXd + i0 + c4];
    w0[kk] = *(const f32x4*)&M0g[(size_t)(kg * 16 + kk) * NXd + i0 + c4];
  }
  f32x4 kw1[2], kw0[2];
#pragma unroll
  for (int j = 0; j < 2; ++j) {
    const int uk = kg * 2 + j;
#pragma unroll
    for (int cc = 0; cc < 4; ++cc) {
      kw1[j][cc] = Kwg[KWL + (i0 + c4 + cc) * NUd + uk];
      kw0[j][cc] = Kwg[(i0 + c4 + cc) * NUd + uk];
    }
  }

  // y-projection weights (2 cols per WG) into LDS
  for (int n = tid; n < NXd * 2; n += 256) {
    int k = n >> 1, q = n & 1;
    sPP[q][k] = PPg[k * NYd + g * 2 + q];
  }

  const float cbr = Cbg[g * 2 + (tid & 1)];
  // bias vectors for the 32 final-reduce threads (4 cols each; same map as c4)
  f32x4 hb0_4 = {0.f, 0.f, 0.f, 0.f}, hb1_4 = {0.f, 0.f, 0.f, 0.f};
  if (tid < 32) {
    hb0_4 = *(const f32x4*)&Hbg[i0 + c4];
    hb1_4 = *(const f32x4*)&Hbg[NXd + i0 + c4];
  }

  // per-thread u element stream: (b0+ub, uk, t), float4-cached over t
  const int ub = tid >> 6, uk = tid & 63;
  const float* Ub = ug + (size_t)(b0 + ub) * (NUd * TTd) + (size_t)uk * TTd;
  float4 ucv = *(const float4*)Ub;
  sU[ub][uk] = ucv.x;  // u_0

  bool gaveup = false;  // sticky: a stuck poll degrades to wrong answer, not a hang

  // Poll-stage this chain's 4x512 G tile (8KB) from LLC into skewed LDS.
  auto stage_g = [&](const float* __restrict__ src, unsigned pbit) {
    const unsigned* p0 = (const unsigned*)(src + tid * 8);
    u32x4 a, b;
    if (!gaveup) {
      int spins = 0;
      for (;;) {
        asm volatile(
            "global_load_dwordx4 %0, %2, off sc0 sc1\n\t"
            "global_load_dwordx4 %1, %2, off offset:16 sc0 sc1\n\t"
            "s_waitcnt vmcnt(0)"
            : "=&v"(a), "=&v"(b)
            : "v"(p0)
            : "memory");
        unsigned m = (a.x ^ pbit) | (a.y ^ pbit) | (a.z ^ pbit) | (a.w ^ pbit) |
                     (b.x ^ pbit) | (b.y ^ pbit) | (b.z ^ pbit) | (b.w ^ pbit);
        if (!(m & 0x80000000u)) break;
        if (++spins > 1000000) { gaveup = true; break; }
        __builtin_amdgcn_s_sleep(1);
      }
    } else {
      asm volatile(
          "global_load_dwordx4 %0, %2, off sc0 sc1\n\t"
          "global_load_dwordx4 %1, %2, off offset:16 sc0 sc1\n\t"
          "s_waitcnt vmcnt(0)"
          : "=&v"(a), "=&v"(b)
          : "v"(p0)
          : "memory");
    }
    const int bb = tid >> 6;
    const int kk = (tid * 8) & 511;
    const int li = kk + ((kk >> 4) << 2);  // skewed index (kk%16 in {0,8})
    u32x4 am = {a.x & 0x7fffffffu, a.y & 0x7fffffffu,
                a.z & 0x7fffffffu, a.w & 0x7fffffffu};
    u32x4 bm = {b.x & 0x7fffffffu, b.y & 0x7fffffffu,
                b.z & 0x7fffffffu, b.w & 0x7fffffffu};
    *(u32x4*)&sG[bb][li] = am;
    *(u32x4*)&sG[bb][li + 4] = bm;
  };

  // Main phase: reg-weight FMAs -> 2-stage LDS reduce -> parity-tagged store.
  auto phase_main = [&](const f32x4* w, const f32x4* kw, const f32x4& hb4,
                        float* __restrict__ Gdst, unsigned pbit) {
    f32x4 acc0 = {0.f, 0.f, 0.f, 0.f}, acc1 = acc0, acc2 = acc0, acc3 = acc0;
    const int gb = kg * 20;  // skewed base of this thread's 16-K slice
#pragma unroll
    for (int blk = 0; blk < 4; ++blk) {
      f32x4 g0 = *(const f32x4*)&sG[0][gb + blk * 4];
      f32x4 g1 = *(const f32x4*)&sG[1][gb + blk * 4];
      f32x4 g2 = *(const f32x4*)&sG[2][gb + blk * 4];
      f32x4 g3 = *(const f32x4*)&sG[3][gb + blk * 4];
#pragma unroll
      for (int q = 0; q < 4; ++q) {
        f32x4 wv = w[blk * 4 + q];
        acc0 += wv * g0[q];
        acc1 += wv * g1[q];
        acc2 += wv * g2[q];
        acc3 += wv * g3[q];
      }
    }
#pragma unroll
    for (int j = 0; j < 2; ++j) {
      f32x4 wv = kw[j];
      const int us = kg * 2 + j;
      acc0 += wv * sU[0][us];
      acc1 += wv * sU[1][us];
      acc2 += wv * sU[2][us];
      acc3 += wv * sU[3][us];
    }
    // stage 1: per-kg partials
    *(f32x4*)&sR1[kg][0][c4] = acc0;
    *(f32x4*)&sR1[kg][1][c4] = acc1;
    *(f32x4*)&sR1[kg][2][c4] = acc2;
    *(f32x4*)&sR1[kg][3][c4] = acc3;
    __syncthreads();
    // stage 2: 32 -> 8 partials (all 256 threads)
    {
      const int kg4 = tid >> 5, r2 = (tid >> 3) & 3, cc = (tid & 7) * 4;
      f32x4 s = *(const f32x4*)&sR1[kg4 * 4 + 0][r2][cc];
      s += *(const f32x4*)&sR1[kg4 * 4 + 1][r2][cc];
      s += *(const f32x4*)&sR1[kg4 * 4 + 2][r2][cc];
      s += *(const f32x4*)&sR1[kg4 * 4 + 3][r2][cc];
      *(f32x4*)&sR2[kg4][r2][cc] = s;
    }
    __syncthreads();
    // stage 3: 8 -> 1, bias, relu, tag, store (32 threads)
    if (tid < 32) {
      const int bb = tid >> 3;  // c4 == (tid&7)*4 already
      f32x4 s = *(const f32x4*)&sR2[0][bb][c4];
#pragma unroll
      for (int k4 = 1; k4 < 8; ++k4) s += *(const f32x4*)&sR2[k4][bb][c4];
      s += hb4;
      u32x4 uv;
      uv.x = __float_as_uint(fmaxf(s.x, 0.f)) | pbit;
      uv.y = __float_as_uint(fmaxf(s.y, 0.f)) | pbit;
      uv.z = __float_as_uint(fmaxf(s.z, 0.f)) | pbit;
      uv.w = __float_as_uint(fmaxf(s.w, 0.f)) | pbit;
      float* gp = Gdst + (size_t)(b0 + bb) * NXd + i0 + c4;
      asm volatile("global_store_dwordx4 %0, %1, off sc0 sc1"
                   :: "v"(gp), "v"(uv) : "memory");
    }
  };

  // y partials + reduce; sG (G2) stays valid until the next stage_g.
  auto y_part = [&](int tOut) {
    if (tid < 64) {
      int ks = tid >> 3, bb = (tid >> 1) & 3, q = tid & 1;
      const int base = ks * 80;  // skewed base of ks*64
      float p = 0.f;
#pragma unroll
      for (int kk = 0; kk < 64; kk += 4) {
        const int li = base + kk + ((kk >> 4) << 2);
        f32x4 gv = *(const f32x4*)&sG[bb][li];
        f32x4 pv = *(const f32x4*)&sPP[q][ks * 64 + kk];
        p = fmaf(gv.x, pv.x, p); p = fmaf(gv.y, pv.y, p);
        p = fmaf(gv.z, pv.z, p); p = fmaf(gv.w, pv.w, p);
      }
      sRedY[ks][bb][q] = p;
    }
    __syncthreads();
    if (tid >= 128 && tid < 136) {
      int r = tid - 128, bb = r >> 1, q = r & 1;  // q == tid&1
      float v = sRedY[0][bb][q] + sRedY[1][bb][q] + sRedY[2][bb][q] +
                sRedY[3][bb][q] + sRedY[4][bb][q] + sRedY[5][bb][q] +
                sRedY[6][bb][q] + sRedY[7][bb][q] + cbr;
      yg[(size_t)(b0 + bb) * (NYd * TTd) + (size_t)(g * 2 + q) * TTd + tOut] = v;
    }
  };

  // Parity schedule (unchanged from round 5): k_init is "B(-1)" at parity 0.
  const float* G1c = G1g + (size_t)b0 * NXd;  // chain-local row base
  const float* G2c = G2g + (size_t)b0 * NXd;
  for (int t = 0; t < TTd - 1; ++t) {
    const unsigned pb = (unsigned)(t & 1) << 31;
    // phase A: G2 = relu(G1@M1 + Hb1 + u_t@Kw1^T)
    stage_g(G1c, pb);
    __syncthreads();
    phase_main(w1, kw1, hb1_4, G2g, pb);

    // phase B: G1 = relu(G2@M0 + Hb0 + u_{t+1}@Kw0^T); y_{t+1} = G2@PP + Cb
    stage_g(G2c, pb);
    {
      int tt = t + 1;
      if ((tt & 3) == 0) ucv = *(const float4*)(Ub + tt);
      int comp = tt & 3;
      float uv = (comp & 2) ? ((comp & 1) ? ucv.w : ucv.z)
                            : ((comp & 1) ? ucv.y : ucv.x);
      sU[ub][uk] = uv;
    }
    __syncthreads();
    phase_main(w0, kw0, hb0_4, G1g, pb ^ 0x80000000u);
    y_part(t + 1);
  }
}

// ---------------- launch ----------------
extern "C" void kernel_launch(void* const* d_in, const int* in_sizes, int n_in,
                              void* d_out, int out_size, void* d_ws, size_t ws_size,
                              hipStream_t stream) {
  (void)in_sizes; (void)n_in; (void)out_size; (void)ws_size;
  const float* u  = (const float*)d_in[0];
  const float* E  = (const float*)d_in[1];
  const float* Kw = (const float*)d_in[2];
  const float* Hw = (const float*)d_in[3];
  const float* Hb = (const float*)d_in[4];
  const float* Cw = (const float*)d_in[5];
  const float* Cb = (const float*)d_in[6];
  float* y = (float*)d_out;
  float* ws = (float*)d_ws;

  float* R0 = ws;                 // 2*LSZ
  float* R1 = ws + 2 * LSZ;       // 2*LSZ
  float* R2 = ws + 4 * LSZ;       // 2*LSZ
  float* M0 = ws + 6 * LSZ;       // LSZ
  float* M1 = M0 + LSZ;           // LSZ
  float* PPb = ws + 8 * LSZ;      // NX*NY
  float* G1 = PPb + NXd * NYd;    // NB*NX
  float* G2 = G1 + NBd * NXd;     // NB*NX

  // Einv via Newton-Schulz: X0 = 2I - E; X_{n+1} = 2X_n - X_n(E X_n), 2 iters
  k_x0<<<dim3((2 * LSZ + 255) / 256), dim3(256), 0, stream>>>(E, R0);
  k_mm<0><<<dim3(8, 8, 2), dim3(256), 0, stream>>>(E, R0, R1);   // T1 = E@X0
  k_mm<1><<<dim3(8, 8, 2), dim3(256), 0, stream>>>(R0, R1, R2);  // X1 = 2X0 - X0@T1
  k_mm<0><<<dim3(8, 8, 2), dim3(256), 0, stream>>>(E, R2, R0);   // T2 = E@X1
  k_mm<1><<<dim3(8, 8, 2), dim3(256), 0, stream>>>(R2, R0, R1);  // X2 = Einv (in R1)

  // M0 = Einv1@Hw0^T, M1 = Einv0@Hw1^T  (z flips the Einv layer)
  k_mm_abt<<<dim3(8, 8, 2), dim3(256), 0, stream>>>(R1 + LSZ, Hw, M0,
                                                    512, 512, -LSZ, LSZ, LSZ);
  // PP = Einv1@Cw^T
  k_mm_abt<<<dim3(1, 8, 1), dim3(256), 0, stream>>>(R1 + LSZ, Cw, PPb,
                                                    32, 32, 0, 0, 0);
  // G1 = relu(Hb0 + u_0@Kw0^T) [parity 0], G2 := parity-1 reset, y[:,:,0] = Cb
  k_init<<<dim3(64), dim3(256), 0, stream>>>(u, Kw, Hb, Cb, G1, (unsigned*)G2, y);
  // serial recurrence, 16 chains x 16 WGs, zero-barrier parity exchange
  k_rnn<<<dim3(256), dim3(256), 0, stream>>>(M0, M1, PPb, u, Kw, Hb, Cb,
                                             G1, G2, y);
}